// Round 4
// baseline (110.731 us; speedup 1.0000x reference)
//
#include <hip/hip_runtime.h>
#include <hip/hip_bf16.h>
#include <math.h>

namespace {

typedef float f32x4 __attribute__((ext_vector_type(4)));
typedef float f32x16 __attribute__((ext_vector_type(16)));
typedef short bf16x8 __attribute__((ext_vector_type(8)));

constexpr int Bc = 32, Nc = 8192, Dc = 128, Kc = 64;
constexpr int PB = 32;            // blocks per batch
constexpr int RPB = Nc / PB;      // 256 rows per block
constexpr int NT = 64;            // rows per iteration tile
constexpr int ITERS = RPB / NT;   // 4
constexpr int XSTR = 136;         // xS row stride in shorts (272 B, 16B-aligned)

// packed bf16 pair via v_cvt_pk_bf16_f32 (compiler-emitted, RNE)
__device__ __forceinline__ unsigned int pk(float a, float b) {
  union { __hip_bfloat162 h; unsigned int u; } c;
  c.h = __float22bfloat162_rn(make_float2(a, b));
  return c.u;
}

// ---------------------------------------------------------------------------
// Kernel 1: per 64-row tile: L2-normalize -> bf16 LDS tile -> MFMA logits
// (W in registers) -> in-wave softmax -> swizzled a^T tile -> MFMA a^T x.
// Block = 256 threads (4 waves); wave w owns logit rows [16w,16w+16) and
// output d-columns [32w, 32w+32). acc[64][128] accumulated in AGPR fragments,
// atomically added into acc[B][K][D] at the end (32 blocks per batch).
// ---------------------------------------------------------------------------
__global__ __launch_bounds__(256, 4) void nv_k1(
    const float* __restrict__ x, const float* __restrict__ conv_w,
    const float* __restrict__ conv_b, float* __restrict__ accA,
    float* __restrict__ asumA) {
  __shared__ __align__(16) short xS[NT * XSTR];  // xn tile, bf16
  __shared__ __align__(16) short aT[Kc * NT];    // a^T tile, bf16, chunk-swizzled
  __shared__ float asumS[4 * 64];

  const int tid = threadIdx.x;
  const int w = tid >> 6, l = tid & 63;
  const int bp = blockIdx.x;  // 0..1023
  const int b = bp / PB, p = bp % PB;
  const float* xb = x + (size_t)b * Nc * Dc + (size_t)p * RPB * Dc;

  // --- conv_w fragments (bf16, B-operand of GEMM1) + bias, held in regs ---
  bf16x8 wf[4][4];
  float cb[4];
#pragma unroll
  for (int nt = 0; nt < 4; ++nt) {
    const int k = (l & 15) + 16 * nt;
    cb[nt] = conv_b[k];
#pragma unroll
    for (int ks = 0; ks < 4; ++ks) {
      const float* wp = conv_w + k * Dc + 8 * (l >> 4) + 32 * ks;
      const float4 w0 = *(const float4*)wp;
      const float4 w1 = *(const float4*)(wp + 4);
      union { unsigned int u[4]; bf16x8 v; } fu;
      fu.u[0] = pk(w0.x, w0.y); fu.u[1] = pk(w0.z, w0.w);
      fu.u[2] = pk(w1.x, w1.y); fu.u[3] = pk(w1.z, w1.w);
      wf[nt][ks] = fu.v;
    }
  }

  f32x16 acc2[2];
#pragma unroll
  for (int mt = 0; mt < 2; ++mt)
#pragma unroll
    for (int r = 0; r < 16; ++r) acc2[mt][r] = 0.f;
  float asum_acc[4] = {0.f, 0.f, 0.f, 0.f};

  // staging: thread owns row sr (0..63), quarter sq (32 floats, contiguous)
  const int sr = tid >> 2, sq = tid & 3;
  float4 cur[8];
  {
    const float* gp = xb + (size_t)sr * Dc + 32 * sq;
#pragma unroll
    for (int j = 0; j < 8; ++j) cur[j] = *(const float4*)(gp + 4 * j);
  }

  const int dcol = (l & 31) + 32 * w;  // this lane's output d-column (GEMM2)

  for (int it = 0; it < ITERS; ++it) {
    // ---- normalize (4-lane shfl reduce) + cvt to bf16 ----
    float ss = 0.f;
#pragma unroll
    for (int j = 0; j < 8; ++j)
      ss += cur[j].x * cur[j].x + cur[j].y * cur[j].y +
            cur[j].z * cur[j].z + cur[j].w * cur[j].w;
    ss += __shfl_xor(ss, 1);
    ss += __shfl_xor(ss, 2);
    const float invn = 1.0f / fmaxf(sqrtf(ss), 1e-12f);
    unsigned int xv[16];
#pragma unroll
    for (int j = 0; j < 8; ++j) {
      xv[2 * j] = pk(cur[j].x * invn, cur[j].y * invn);
      xv[2 * j + 1] = pk(cur[j].z * invn, cur[j].w * invn);
    }
    __syncthreads();  // previous iteration's GEMM2 done with xS/aT
    {
      short* dst = xS + sr * XSTR + 32 * sq;
#pragma unroll
      for (int j = 0; j < 4; ++j) {
        union { unsigned int u[4]; bf16x8 v; } fu;
        fu.u[0] = xv[4 * j]; fu.u[1] = xv[4 * j + 1];
        fu.u[2] = xv[4 * j + 2]; fu.u[3] = xv[4 * j + 3];
        *(bf16x8*)(dst + 8 * j) = fu.v;
      }
    }
    // prefetch next tile (in flight across GEMM phases)
    if (it + 1 < ITERS) {
      const float* gp = xb + (size_t)((it + 1) * NT + sr) * Dc + 32 * sq;
#pragma unroll
      for (int j = 0; j < 8; ++j) cur[j] = *(const float4*)(gp + 4 * j);
    }
    __syncthreads();  // xS ready

    // ---- GEMM1: logits[16 rows x 64 k] for wave w ----
    f32x4 c1[4];
#pragma unroll
    for (int nt = 0; nt < 4; ++nt) {
      c1[nt][0] = 0.f; c1[nt][1] = 0.f; c1[nt][2] = 0.f; c1[nt][3] = 0.f;
    }
#pragma unroll
    for (int ks = 0; ks < 4; ++ks) {
      const bf16x8 af =
          *(const bf16x8*)(xS + (16 * w + (l & 15)) * XSTR + 8 * (l >> 4) + 32 * ks);
#pragma unroll
      for (int nt = 0; nt < 4; ++nt)
        c1[nt] = __builtin_amdgcn_mfma_f32_16x16x32_bf16(af, wf[nt][ks],
                                                         c1[nt], 0, 0, 0);
    }

    // ---- softmax (in-lane + 16-lane-group shfl); rows n = 16w+4*(l>>4)+i ----
    float a4[4][4];
#pragma unroll
    for (int nt = 0; nt < 4; ++nt)
#pragma unroll
      for (int i = 0; i < 4; ++i) a4[nt][i] = c1[nt][i] + cb[nt];
#pragma unroll
    for (int i = 0; i < 4; ++i) {
      float mx = fmaxf(fmaxf(a4[0][i], a4[1][i]), fmaxf(a4[2][i], a4[3][i]));
      mx = fmaxf(mx, __shfl_xor(mx, 1));
      mx = fmaxf(mx, __shfl_xor(mx, 2));
      mx = fmaxf(mx, __shfl_xor(mx, 4));
      mx = fmaxf(mx, __shfl_xor(mx, 8));
      float s = 0.f;
#pragma unroll
      for (int nt = 0; nt < 4; ++nt) {
        a4[nt][i] = __expf(a4[nt][i] - mx);
        s += a4[nt][i];
      }
      s += __shfl_xor(s, 1);
      s += __shfl_xor(s, 2);
      s += __shfl_xor(s, 4);
      s += __shfl_xor(s, 8);
      const float inv = __builtin_amdgcn_rcpf(s);
#pragma unroll
      for (int nt = 0; nt < 4; ++nt) a4[nt][i] *= inv;
    }
    // ---- asum accumulate + a^T tile write (swizzled chunks) ----
#pragma unroll
    for (int nt = 0; nt < 4; ++nt) {
      float s = a4[nt][0] + a4[nt][1] + a4[nt][2] + a4[nt][3];
      s += __shfl_xor(s, 16);
      s += __shfl_xor(s, 32);
      asum_acc[nt] += s;
      const int k = (l & 15) + 16 * nt;
      const int cn = 4 * w + (l >> 4);  // n-chunk (4 rows)
      const unsigned int u0 = pk(a4[nt][0], a4[nt][1]);
      const unsigned int u1 = pk(a4[nt][2], a4[nt][3]);
      *(uint2*)(aT + k * NT + ((cn ^ (l & 15)) << 2)) = make_uint2(u0, u1);
    }
    __syncthreads();  // aT ready

    // ---- GEMM2: acc[k][d] += a^T[k][n] * xn[n][d], 32x32x16 ----
#pragma unroll
    for (int ks2 = 0; ks2 < 4; ++ks2) {
      const int n0 = 16 * ks2 + 8 * (l >> 5);
      union { unsigned int u[4]; bf16x8 v; } bu;
#pragma unroll
      for (int j = 0; j < 4; ++j) {
        const unsigned short s0 =
            *(const unsigned short*)(xS + (n0 + 2 * j) * XSTR + dcol);
        const unsigned short s1 =
            *(const unsigned short*)(xS + (n0 + 2 * j + 1) * XSTR + dcol);
        bu.u[j] = (unsigned int)s0 | ((unsigned int)s1 << 16);
      }
#pragma unroll
      for (int mt = 0; mt < 2; ++mt) {
        const int k = (l & 31) + 32 * mt;
        const int cn = n0 >> 2;
        const uint2 lo = *(const uint2*)(aT + k * NT + (((cn)     ^ (k & 15)) << 2));
        const uint2 hi = *(const uint2*)(aT + k * NT + (((cn + 1) ^ (k & 15)) << 2));
        union { unsigned int u[4]; bf16x8 v; } au;
        au.u[0] = lo.x; au.u[1] = lo.y; au.u[2] = hi.x; au.u[3] = hi.y;
        acc2[mt] = __builtin_amdgcn_mfma_f32_32x32x16_bf16(au.v, bu.v,
                                                           acc2[mt], 0, 0, 0);
      }
    }
    // next iteration's top barrier protects xS/aT from overwrite
  }

  // ---- epilogue: asum combine + atomic accumulation into acc[B][K][D] ----
#pragma unroll
  for (int nt = 0; nt < 4; ++nt)
    if (l < 16) asumS[w * 64 + nt * 16 + (l & 15)] = asum_acc[nt];
  __syncthreads();
  if (tid < 64)
    atomicAdd(&asumA[(size_t)b * Kc + tid],
              asumS[tid] + asumS[64 + tid] + asumS[128 + tid] + asumS[192 + tid]);

  float* ap = accA + (size_t)b * (Kc * Dc);
#pragma unroll
  for (int mt = 0; mt < 2; ++mt)
#pragma unroll
    for (int r = 0; r < 16; ++r) {
      const int k = 32 * mt + (r & 3) + 8 * (r >> 2) + 4 * (l >> 5);
      atomicAdd(&ap[k * Dc + dcol], acc2[mt][r]);
    }
}

// ---------------------------------------------------------------------------
// Kernel 2: subtract centroid*asum, intra-normalize over D, write out;
// emit per-(b,kg) sum-of-squares for the global norm.
// ---------------------------------------------------------------------------
__global__ __launch_bounds__(256) void nv_k2(
    const float* __restrict__ accA, const float* __restrict__ asumA,
    const float* __restrict__ cent, float* __restrict__ out,
    float* __restrict__ gssP) {
  __shared__ float asumS[8];
  __shared__ float gssWv[4];
  const int tid = threadIdx.x;
  const int w = tid >> 6, l = tid & 63;
  const int b = blockIdx.x >> 3;
  const int kg = blockIdx.x & 7;

  if (tid < 8) asumS[tid] = asumA[(size_t)b * Kc + kg * 8 + tid];
  __syncthreads();

  float gss = 0.f;
#pragma unroll
  for (int ki = 0; ki < 2; ++ki) {
    const int kloc = w + 4 * ki, k = kg * 8 + kloc;
    const float2 t = *(const float2*)(accA + (size_t)b * (Kc * Dc) + k * Dc + 2 * l);
    const float as = asumS[kloc];
    const float2 c2 = *(const float2*)(cent + (size_t)k * Dc + 2 * l);
    float v0 = t.x - c2.x * as;
    float v1 = t.y - c2.y * as;
    float ssk = v0 * v0 + v1 * v1;
#pragma unroll
    for (int o = 1; o < 64; o <<= 1) ssk += __shfl_xor(ssk, o);
    const float sc = 1.0f / fmaxf(sqrtf(ssk), 1e-12f);
    gss += ssk * sc * sc;
    float2* o2 =
        reinterpret_cast<float2*>(out + (size_t)b * (Kc * Dc) + k * Dc + 2 * l);
    *o2 = make_float2(v0 * sc, v1 * sc);
  }
  if (l == 0) gssWv[w] = gss;
  __syncthreads();
  if (tid == 0) gssP[blockIdx.x] = gssWv[0] + gssWv[1] + gssWv[2] + gssWv[3];
}

// ---------------------------------------------------------------------------
// Kernel 3: global L2 normalization.
// ---------------------------------------------------------------------------
__global__ __launch_bounds__(256) void nv_k3(float* __restrict__ out,
                                             const float* __restrict__ gssP) {
  const int bid = blockIdx.x;
  const int b = bid >> 3;
  float g = 0.f;
#pragma unroll
  for (int i = 0; i < 8; ++i) g += gssP[b * 8 + i];
  const float gsc = 1.0f / fmaxf(sqrtf(g), 1e-12f);
  float4* o4 = reinterpret_cast<float4*>(out) + (size_t)bid * 256 + threadIdx.x;
  float4 v = *o4;
  v.x *= gsc;
  v.y *= gsc;
  v.z *= gsc;
  v.w *= gsc;
  *o4 = v;
}

}  // namespace

extern "C" void kernel_launch(void* const* d_in, const int* in_sizes, int n_in,
                              void* d_out, int out_size, void* d_ws,
                              size_t ws_size, hipStream_t stream) {
  const float* x = (const float*)d_in[0];
  const float* ce = (const float*)d_in[1];
  const float* cw = (const float*)d_in[2];
  const float* cb = (const float*)d_in[3];
  float* out = (float*)d_out;

  const size_t accf = (size_t)Bc * Kc * Dc;  // 262144 floats (1 MB)
  const size_t asumf = (size_t)Bc * Kc;      // 2048 floats
  float* accA = (float*)d_ws;
  float* asumA = accA + accf;
  float* gssP = asumA + asumf;

  (void)hipMemsetAsync(d_ws, 0, (accf + asumf) * sizeof(float), stream);
  nv_k1<<<Bc * PB, 256, 0, stream>>>(x, cw, cb, accA, asumA);
  nv_k2<<<Bc * 8, 256, 0, stream>>>(accA, asumA, ce, out, gssP);
  nv_k3<<<256, 256, 0, stream>>>(out, gssP);
}

// Round 5
// 107.735 us; speedup vs baseline: 1.0278x; 1.0278x over previous
//
#include <hip/hip_runtime.h>
#include <hip/hip_bf16.h>
#include <math.h>

namespace {

typedef float f32x4 __attribute__((ext_vector_type(4)));
typedef float f32x16 __attribute__((ext_vector_type(16)));
typedef short bf16x8 __attribute__((ext_vector_type(8)));

constexpr int Bc = 32, Nc = 8192, Dc = 128, Kc = 64;
constexpr int PB = 32;            // blocks per batch
constexpr int RPB = Nc / PB;      // 256 rows per block
constexpr int NT = 64;            // rows per iteration tile
constexpr int ITERS = RPB / NT;   // 4
constexpr int XSTR = 136;         // xS row stride in shorts (272 B, 16B-aligned)

// packed bf16 pair via v_cvt_pk_bf16_f32 (compiler-emitted, RNE)
__device__ __forceinline__ unsigned int pk(float a, float b) {
  union { __hip_bfloat162 h; unsigned int u; } c;
  c.h = __float22bfloat162_rn(make_float2(a, b));
  return c.u;
}

// ---------------------------------------------------------------------------
// Kernel 0: pre-pack conv_w into GEMM1 B-fragment layout (bf16, uint4 per
// lane-fragment). Table: [nt*4+ks][lane] -> 16 B. Total 16 KB, L2-resident.
// Fragment (nt,ks,lane): conv_w[k=(lane&15)+16nt][8*(lane>>4)+32*ks .. +8].
// ---------------------------------------------------------------------------
__global__ __launch_bounds__(256) void nv_k0(const float* __restrict__ conv_w,
                                             uint4* __restrict__ wpk) {
  const int t = blockIdx.x * 256 + threadIdx.x;  // 0..1023
  const int lane = t & 63, frag = t >> 6;        // frag = nt*4+ks
  const int nt = frag >> 2, ks = frag & 3;
  const int k = (lane & 15) + 16 * nt;
  const float* wp = conv_w + k * Dc + 8 * (lane >> 4) + 32 * ks;
  const float4 w0 = *(const float4*)wp;
  const float4 w1 = *(const float4*)(wp + 4);
  wpk[frag * 64 + lane] =
      make_uint4(pk(w0.x, w0.y), pk(w0.z, w0.w), pk(w1.x, w1.y), pk(w1.z, w1.w));
}

// ---------------------------------------------------------------------------
// Kernel 1: per 64-row tile: L2-normalize -> bf16 LDS tile -> MFMA logits
// (W fragments streamed from L2-resident packed table) -> in-wave softmax ->
// swizzled a^T tile -> MFMA a^T x. Block = 256 threads (4 waves); wave w owns
// logit rows [16w,16w+16) and output d-columns [32w,32w+32). acc[64][128] in
// AGPR fragments, atomically added into acc[B][K][D] (32 blocks per batch).
// ---------------------------------------------------------------------------
__global__ __launch_bounds__(256, 4) void nv_k1(
    const float* __restrict__ x, const uint4* __restrict__ wpk,
    const float* __restrict__ conv_b, float* __restrict__ accA,
    float* __restrict__ asumA) {
  __shared__ __align__(16) short xS[NT * XSTR];  // xn tile, bf16
  __shared__ __align__(16) short aT[Kc * NT];    // a^T tile, bf16, chunk-swizzled
  __shared__ float asumS[4 * 64];

  const int tid = threadIdx.x;
  const int w = tid >> 6, l = tid & 63;
  const int bp = blockIdx.x;  // 0..1023
  const int b = bp / PB, p = bp % PB;
  const float* xb = x + (size_t)b * Nc * Dc + (size_t)p * RPB * Dc;

  // bias per nt (lane's cluster k = (l&15)+16nt)
  float cb[4];
#pragma unroll
  for (int nt = 0; nt < 4; ++nt) cb[nt] = conv_b[(l & 15) + 16 * nt];

  f32x16 acc2[2];
#pragma unroll
  for (int mt = 0; mt < 2; ++mt)
#pragma unroll
    for (int r = 0; r < 16; ++r) acc2[mt][r] = 0.f;
  float asum_acc[4] = {0.f, 0.f, 0.f, 0.f};

  // staging: thread owns row sr (0..63), quarter sq (32 floats, contiguous)
  const int sr = tid >> 2, sq = tid & 3;
  float4 cur[8];
  {
    const float* gp = xb + (size_t)sr * Dc + 32 * sq;
#pragma unroll
    for (int j = 0; j < 8; ++j) cur[j] = *(const float4*)(gp + 4 * j);
  }

  const int dcol = (l & 31) + 32 * w;  // this lane's output d-column (GEMM2)

  for (int it = 0; it < ITERS; ++it) {
    // ---- normalize (4-lane shfl reduce) + cvt to bf16 ----
    float ss = 0.f;
#pragma unroll
    for (int j = 0; j < 8; ++j)
      ss += cur[j].x * cur[j].x + cur[j].y * cur[j].y +
            cur[j].z * cur[j].z + cur[j].w * cur[j].w;
    ss += __shfl_xor(ss, 1);
    ss += __shfl_xor(ss, 2);
    const float invn = 1.0f / fmaxf(sqrtf(ss), 1e-12f);
    unsigned int xv[16];
#pragma unroll
    for (int j = 0; j < 8; ++j) {
      xv[2 * j] = pk(cur[j].x * invn, cur[j].y * invn);
      xv[2 * j + 1] = pk(cur[j].z * invn, cur[j].w * invn);
    }
    __syncthreads();  // previous iteration's GEMM2 done with xS/aT
    {
      short* dst = xS + sr * XSTR + 32 * sq;
#pragma unroll
      for (int j = 0; j < 4; ++j) {
        union { unsigned int u[4]; bf16x8 v; } fu;
        fu.u[0] = xv[4 * j]; fu.u[1] = xv[4 * j + 1];
        fu.u[2] = xv[4 * j + 2]; fu.u[3] = xv[4 * j + 3];
        *(bf16x8*)(dst + 8 * j) = fu.v;
      }
    }
    // prefetch next tile (in flight across GEMM phases)
    if (it + 1 < ITERS) {
      const float* gp = xb + (size_t)((it + 1) * NT + sr) * Dc + 32 * sq;
#pragma unroll
      for (int j = 0; j < 8; ++j) cur[j] = *(const float4*)(gp + 4 * j);
    }
    __syncthreads();  // xS ready

    // ---- GEMM1: logits[16 rows x 64 k] for wave w; W streamed from L2 ----
    f32x4 c1[4];
#pragma unroll
    for (int nt = 0; nt < 4; ++nt) {
      c1[nt][0] = 0.f; c1[nt][1] = 0.f; c1[nt][2] = 0.f; c1[nt][3] = 0.f;
    }
#pragma unroll
    for (int ks = 0; ks < 4; ++ks) {
      const bf16x8 af =
          *(const bf16x8*)(xS + (16 * w + (l & 15)) * XSTR + 8 * (l >> 4) + 32 * ks);
      union { uint4 q; bf16x8 v; } wu0, wu1, wu2, wu3;
      wu0.q = wpk[(0 * 4 + ks) * 64 + l];
      wu1.q = wpk[(1 * 4 + ks) * 64 + l];
      wu2.q = wpk[(2 * 4 + ks) * 64 + l];
      wu3.q = wpk[(3 * 4 + ks) * 64 + l];
      c1[0] = __builtin_amdgcn_mfma_f32_16x16x32_bf16(af, wu0.v, c1[0], 0, 0, 0);
      c1[1] = __builtin_amdgcn_mfma_f32_16x16x32_bf16(af, wu1.v, c1[1], 0, 0, 0);
      c1[2] = __builtin_amdgcn_mfma_f32_16x16x32_bf16(af, wu2.v, c1[2], 0, 0, 0);
      c1[3] = __builtin_amdgcn_mfma_f32_16x16x32_bf16(af, wu3.v, c1[3], 0, 0, 0);
    }

    // ---- softmax (in-lane + 16-lane-group shfl); rows n = 16w+4*(l>>4)+i ----
    float a4[4][4];
#pragma unroll
    for (int nt = 0; nt < 4; ++nt)
#pragma unroll
      for (int i = 0; i < 4; ++i) a4[nt][i] = c1[nt][i] + cb[nt];
#pragma unroll
    for (int i = 0; i < 4; ++i) {
      float mx = fmaxf(fmaxf(a4[0][i], a4[1][i]), fmaxf(a4[2][i], a4[3][i]));
      mx = fmaxf(mx, __shfl_xor(mx, 1));
      mx = fmaxf(mx, __shfl_xor(mx, 2));
      mx = fmaxf(mx, __shfl_xor(mx, 4));
      mx = fmaxf(mx, __shfl_xor(mx, 8));
      float s = 0.f;
#pragma unroll
      for (int nt = 0; nt < 4; ++nt) {
        a4[nt][i] = __expf(a4[nt][i] - mx);
        s += a4[nt][i];
      }
      s += __shfl_xor(s, 1);
      s += __shfl_xor(s, 2);
      s += __shfl_xor(s, 4);
      s += __shfl_xor(s, 8);
      const float inv = __builtin_amdgcn_rcpf(s);
#pragma unroll
      for (int nt = 0; nt < 4; ++nt) a4[nt][i] *= inv;
    }
    // ---- asum accumulate + a^T tile write (swizzled chunks) ----
#pragma unroll
    for (int nt = 0; nt < 4; ++nt) {
      float s = a4[nt][0] + a4[nt][1] + a4[nt][2] + a4[nt][3];
      s += __shfl_xor(s, 16);
      s += __shfl_xor(s, 32);
      asum_acc[nt] += s;
      const int k = (l & 15) + 16 * nt;
      const int cn = 4 * w + (l >> 4);  // n-chunk (4 rows)
      const unsigned int u0 = pk(a4[nt][0], a4[nt][1]);
      const unsigned int u1 = pk(a4[nt][2], a4[nt][3]);
      *(uint2*)(aT + k * NT + ((cn ^ (l & 15)) << 2)) = make_uint2(u0, u1);
    }
    __syncthreads();  // aT ready

    // ---- GEMM2: acc[k][d] += a^T[k][n] * xn[n][d], 32x32x16 ----
#pragma unroll
    for (int ks2 = 0; ks2 < 4; ++ks2) {
      const int n0 = 16 * ks2 + 8 * (l >> 5);
      union { unsigned int u[4]; bf16x8 v; } bu;
#pragma unroll
      for (int j = 0; j < 4; ++j) {
        const unsigned short s0 =
            *(const unsigned short*)(xS + (n0 + 2 * j) * XSTR + dcol);
        const unsigned short s1 =
            *(const unsigned short*)(xS + (n0 + 2 * j + 1) * XSTR + dcol);
        bu.u[j] = (unsigned int)s0 | ((unsigned int)s1 << 16);
      }
#pragma unroll
      for (int mt = 0; mt < 2; ++mt) {
        const int k = (l & 31) + 32 * mt;
        const int cn = n0 >> 2;
        const uint2 lo = *(const uint2*)(aT + k * NT + (((cn)     ^ (k & 15)) << 2));
        const uint2 hi = *(const uint2*)(aT + k * NT + (((cn + 1) ^ (k & 15)) << 2));
        union { unsigned int u[4]; bf16x8 v; } au;
        au.u[0] = lo.x; au.u[1] = lo.y; au.u[2] = hi.x; au.u[3] = hi.y;
        acc2[mt] = __builtin_amdgcn_mfma_f32_32x32x16_bf16(au.v, bu.v,
                                                           acc2[mt], 0, 0, 0);
      }
    }
    // next iteration's top barrier protects xS/aT from overwrite
  }

  // ---- epilogue: asum combine + atomic accumulation into acc[B][K][D] ----
#pragma unroll
  for (int nt = 0; nt < 4; ++nt)
    if (l < 16) asumS[w * 64 + nt * 16 + (l & 15)] = asum_acc[nt];
  __syncthreads();
  if (tid < 64)
    atomicAdd(&asumA[(size_t)b * Kc + tid],
              asumS[tid] + asumS[64 + tid] + asumS[128 + tid] + asumS[192 + tid]);

  float* ap = accA + (size_t)b * (Kc * Dc);
#pragma unroll
  for (int mt = 0; mt < 2; ++mt)
#pragma unroll
    for (int r = 0; r < 16; ++r) {
      const int k = 32 * mt + (r & 3) + 8 * (r >> 2) + 4 * (l >> 5);
      atomicAdd(&ap[k * Dc + dcol], acc2[mt][r]);
    }
}

// ---------------------------------------------------------------------------
// Kernel 2: subtract centroid*asum, intra-normalize over D, write out;
// emit per-(b,kg) sum-of-squares for the global norm.
// ---------------------------------------------------------------------------
__global__ __launch_bounds__(256) void nv_k2(
    const float* __restrict__ accA, const float* __restrict__ asumA,
    const float* __restrict__ cent, float* __restrict__ out,
    float* __restrict__ gssP) {
  __shared__ float asumS[8];
  __shared__ float gssWv[4];
  const int tid = threadIdx.x;
  const int w = tid >> 6, l = tid & 63;
  const int b = blockIdx.x >> 3;
  const int kg = blockIdx.x & 7;

  if (tid < 8) asumS[tid] = asumA[(size_t)b * Kc + kg * 8 + tid];
  __syncthreads();

  float gss = 0.f;
#pragma unroll
  for (int ki = 0; ki < 2; ++ki) {
    const int kloc = w + 4 * ki, k = kg * 8 + kloc;
    const float2 t = *(const float2*)(accA + (size_t)b * (Kc * Dc) + k * Dc + 2 * l);
    const float as = asumS[kloc];
    const float2 c2 = *(const float2*)(cent + (size_t)k * Dc + 2 * l);
    float v0 = t.x - c2.x * as;
    float v1 = t.y - c2.y * as;
    float ssk = v0 * v0 + v1 * v1;
#pragma unroll
    for (int o = 1; o < 64; o <<= 1) ssk += __shfl_xor(ssk, o);
    const float sc = 1.0f / fmaxf(sqrtf(ssk), 1e-12f);
    gss += ssk * sc * sc;
    float2* o2 =
        reinterpret_cast<float2*>(out + (size_t)b * (Kc * Dc) + k * Dc + 2 * l);
    *o2 = make_float2(v0 * sc, v1 * sc);
  }
  if (l == 0) gssWv[w] = gss;
  __syncthreads();
  if (tid == 0) gssP[blockIdx.x] = gssWv[0] + gssWv[1] + gssWv[2] + gssWv[3];
}

// ---------------------------------------------------------------------------
// Kernel 3: global L2 normalization.
// ---------------------------------------------------------------------------
__global__ __launch_bounds__(256) void nv_k3(float* __restrict__ out,
                                             const float* __restrict__ gssP) {
  const int bid = blockIdx.x;
  const int b = bid >> 3;
  float g = 0.f;
#pragma unroll
  for (int i = 0; i < 8; ++i) g += gssP[b * 8 + i];
  const float gsc = 1.0f / fmaxf(sqrtf(g), 1e-12f);
  float4* o4 = reinterpret_cast<float4*>(out) + (size_t)bid * 256 + threadIdx.x;
  float4 v = *o4;
  v.x *= gsc;
  v.y *= gsc;
  v.z *= gsc;
  v.w *= gsc;
  *o4 = v;
}

}  // namespace

extern "C" void kernel_launch(void* const* d_in, const int* in_sizes, int n_in,
                              void* d_out, int out_size, void* d_ws,
                              size_t ws_size, hipStream_t stream) {
  const float* x = (const float*)d_in[0];
  const float* ce = (const float*)d_in[1];
  const float* cw = (const float*)d_in[2];
  const float* cb = (const float*)d_in[3];
  float* out = (float*)d_out;

  const size_t accf = (size_t)Bc * Kc * Dc;  // 262144 floats (1 MB)
  const size_t asumf = (size_t)Bc * Kc;      // 2048 floats
  const size_t gssf = (size_t)Bc * 8;        // 256 floats
  float* accA = (float*)d_ws;
  float* asumA = accA + accf;
  float* gssP = asumA + asumf;
  uint4* wpk = (uint4*)(gssP + gssf);        // 1024 x 16 B = 16 KB

  (void)hipMemsetAsync(d_ws, 0, (accf + asumf) * sizeof(float), stream);
  nv_k0<<<4, 256, 0, stream>>>(cw, wpk);
  nv_k1<<<Bc * PB, 256, 0, stream>>>(x, wpk, cb, accA, asumA);
  nv_k2<<<Bc * 8, 256, 0, stream>>>(accA, asumA, ce, out, gssP);
  nv_k3<<<256, 256, 0, stream>>>(out, gssP);
}

// Round 6
// 96.554 us; speedup vs baseline: 1.1468x; 1.1158x over previous
//
#include <hip/hip_runtime.h>
#include <hip/hip_bf16.h>
#include <math.h>

namespace {

typedef float f32x4 __attribute__((ext_vector_type(4)));
typedef float f32x16 __attribute__((ext_vector_type(16)));
typedef short bf16x8 __attribute__((ext_vector_type(8)));

constexpr int Bc = 32, Nc = 8192, Dc = 128, Kc = 64;
constexpr int PB = 32;            // blocks per batch
constexpr int RPB = Nc / PB;      // 256 rows per block
constexpr int NT = 64;            // rows per iteration tile
constexpr int ITERS = RPB / NT;   // 4
constexpr int XSTR = 136;         // xS row stride in shorts (272 B, 16B-aligned)

// packed bf16 pair via v_cvt_pk_bf16_f32 (compiler-emitted, RNE)
__device__ __forceinline__ unsigned int pk(float a, float b) {
  union { __hip_bfloat162 h; unsigned int u; } c;
  c.h = __float22bfloat162_rn(make_float2(a, b));
  return c.u;
}

// ---------------------------------------------------------------------------
// Kernel 0: pre-pack conv_w into GEMM1 B-fragment layout (bf16, uint4 per
// lane-fragment). Table: [nt*4+ks][lane] -> 16 B. Total 16 KB, L2-resident.
// ---------------------------------------------------------------------------
__global__ __launch_bounds__(256) void nv_k0(const float* __restrict__ conv_w,
                                             uint4* __restrict__ wpk) {
  const int t = blockIdx.x * 256 + threadIdx.x;  // 0..1023
  const int lane = t & 63, frag = t >> 6;        // frag = nt*4+ks
  const int nt = frag >> 2, ks = frag & 3;
  const int k = (lane & 15) + 16 * nt;
  const float* wp = conv_w + k * Dc + 8 * (lane >> 4) + 32 * ks;
  const float4 w0 = *(const float4*)wp;
  const float4 w1 = *(const float4*)(wp + 4);
  wpk[frag * 64 + lane] =
      make_uint4(pk(w0.x, w0.y), pk(w0.z, w0.w), pk(w1.x, w1.y), pk(w1.z, w1.w));
}

// ---------------------------------------------------------------------------
// Kernel 1: per 64-row tile: load -> L2-normalize -> bf16 LDS tile -> MFMA
// logits (W fragments from L2 table) -> in-wave softmax -> swizzled a^T tile
// -> MFMA a^T x. Block = 256 threads (4 waves). No persistent prefetch:
// tile load sits at iteration top; 16 waves/CU of TLP hides the latency.
// acc[64][128] in fragments, atomically added into acc[B][K][D].
// ---------------------------------------------------------------------------
__global__ __launch_bounds__(256, 4) void nv_k1(
    const float* __restrict__ x, const uint4* __restrict__ wpk,
    const float* __restrict__ conv_b, float* __restrict__ accA,
    float* __restrict__ asumA) {
  __shared__ __align__(16) short xS[NT * XSTR];  // xn tile, bf16
  __shared__ __align__(16) short aT[Kc * NT];    // a^T tile, bf16, chunk-swizzled
  __shared__ float asumS[4 * 64];

  const int tid = threadIdx.x;
  const int w = tid >> 6, l = tid & 63;
  const int bp = blockIdx.x;  // 0..1023
  const int b = bp / PB, p = bp % PB;
  const float* xb = x + (size_t)b * Nc * Dc + (size_t)p * RPB * Dc;

  // bias per nt (lane's cluster k = (l&15)+16nt)
  float cb[4];
#pragma unroll
  for (int nt = 0; nt < 4; ++nt) cb[nt] = conv_b[(l & 15) + 16 * nt];

  f32x16 acc2[2];
#pragma unroll
  for (int mt = 0; mt < 2; ++mt)
#pragma unroll
    for (int r = 0; r < 16; ++r) acc2[mt][r] = 0.f;
  float asum_acc[4] = {0.f, 0.f, 0.f, 0.f};

  // staging: thread owns row sr (0..63), quarter sq (32 floats, contiguous)
  const int sr = tid >> 2, sq = tid & 3;
  const int dcol = (l & 31) + 32 * w;  // this lane's output d-column (GEMM2)

  for (int it = 0; it < ITERS; ++it) {
    // ---- load tile (no persistent prefetch; TLP hides latency) ----
    float4 cur[8];
    {
      const float* gp = xb + (size_t)(it * NT + sr) * Dc + 32 * sq;
#pragma unroll
      for (int j = 0; j < 8; ++j) cur[j] = *(const float4*)(gp + 4 * j);
    }
    // ---- normalize (4-lane shfl reduce) + cvt to bf16 ----
    float ss = 0.f;
#pragma unroll
    for (int j = 0; j < 8; ++j)
      ss += cur[j].x * cur[j].x + cur[j].y * cur[j].y +
            cur[j].z * cur[j].z + cur[j].w * cur[j].w;
    ss += __shfl_xor(ss, 1);
    ss += __shfl_xor(ss, 2);
    const float invn = 1.0f / fmaxf(sqrtf(ss), 1e-12f);
    unsigned int xv[16];
#pragma unroll
    for (int j = 0; j < 8; ++j) {
      xv[2 * j] = pk(cur[j].x * invn, cur[j].y * invn);
      xv[2 * j + 1] = pk(cur[j].z * invn, cur[j].w * invn);
    }
    __syncthreads();  // previous iteration's GEMM2 done with xS/aT
    {
      short* dst = xS + sr * XSTR + 32 * sq;
#pragma unroll
      for (int j = 0; j < 4; ++j) {
        union { unsigned int u[4]; bf16x8 v; } fu;
        fu.u[0] = xv[4 * j]; fu.u[1] = xv[4 * j + 1];
        fu.u[2] = xv[4 * j + 2]; fu.u[3] = xv[4 * j + 3];
        *(bf16x8*)(dst + 8 * j) = fu.v;
      }
    }
    __syncthreads();  // xS ready

    // ---- GEMM1: logits[16 rows x 64 k] for wave w; W streamed from L2 ----
    f32x4 c1[4];
#pragma unroll
    for (int nt = 0; nt < 4; ++nt) {
      c1[nt][0] = 0.f; c1[nt][1] = 0.f; c1[nt][2] = 0.f; c1[nt][3] = 0.f;
    }
#pragma unroll
    for (int ks = 0; ks < 4; ++ks) {
      const bf16x8 af =
          *(const bf16x8*)(xS + (16 * w + (l & 15)) * XSTR + 8 * (l >> 4) + 32 * ks);
      union { uint4 q; bf16x8 v; } wu0, wu1, wu2, wu3;
      wu0.q = wpk[(0 * 4 + ks) * 64 + l];
      wu1.q = wpk[(1 * 4 + ks) * 64 + l];
      wu2.q = wpk[(2 * 4 + ks) * 64 + l];
      wu3.q = wpk[(3 * 4 + ks) * 64 + l];
      c1[0] = __builtin_amdgcn_mfma_f32_16x16x32_bf16(af, wu0.v, c1[0], 0, 0, 0);
      c1[1] = __builtin_amdgcn_mfma_f32_16x16x32_bf16(af, wu1.v, c1[1], 0, 0, 0);
      c1[2] = __builtin_amdgcn_mfma_f32_16x16x32_bf16(af, wu2.v, c1[2], 0, 0, 0);
      c1[3] = __builtin_amdgcn_mfma_f32_16x16x32_bf16(af, wu3.v, c1[3], 0, 0, 0);
    }

    // ---- softmax (in-lane + 16-lane-group shfl); rows n = 16w+4*(l>>4)+i ----
    float a4[4][4];
#pragma unroll
    for (int nt = 0; nt < 4; ++nt)
#pragma unroll
      for (int i = 0; i < 4; ++i) a4[nt][i] = c1[nt][i] + cb[nt];
#pragma unroll
    for (int i = 0; i < 4; ++i) {
      float mx = fmaxf(fmaxf(a4[0][i], a4[1][i]), fmaxf(a4[2][i], a4[3][i]));
      mx = fmaxf(mx, __shfl_xor(mx, 1));
      mx = fmaxf(mx, __shfl_xor(mx, 2));
      mx = fmaxf(mx, __shfl_xor(mx, 4));
      mx = fmaxf(mx, __shfl_xor(mx, 8));
      float s = 0.f;
#pragma unroll
      for (int nt = 0; nt < 4; ++nt) {
        a4[nt][i] = __expf(a4[nt][i] - mx);
        s += a4[nt][i];
      }
      s += __shfl_xor(s, 1);
      s += __shfl_xor(s, 2);
      s += __shfl_xor(s, 4);
      s += __shfl_xor(s, 8);
      const float inv = __builtin_amdgcn_rcpf(s);
#pragma unroll
      for (int nt = 0; nt < 4; ++nt) a4[nt][i] *= inv;
    }
    // ---- asum accumulate + a^T tile write (swizzled chunks) ----
#pragma unroll
    for (int nt = 0; nt < 4; ++nt) {
      float s = a4[nt][0] + a4[nt][1] + a4[nt][2] + a4[nt][3];
      s += __shfl_xor(s, 16);
      s += __shfl_xor(s, 32);
      asum_acc[nt] += s;
      const int k = (l & 15) + 16 * nt;
      const int cn = 4 * w + (l >> 4);  // n-chunk (4 rows)
      const unsigned int u0 = pk(a4[nt][0], a4[nt][1]);
      const unsigned int u1 = pk(a4[nt][2], a4[nt][3]);
      *(uint2*)(aT + k * NT + ((cn ^ (l & 15)) << 2)) = make_uint2(u0, u1);
    }
    __syncthreads();  // aT ready

    // ---- GEMM2: acc[k][d] += a^T[k][n] * xn[n][d], 32x32x16 ----
#pragma unroll
    for (int ks2 = 0; ks2 < 4; ++ks2) {
      const int n0 = 16 * ks2 + 8 * (l >> 5);
      union { unsigned int u[4]; bf16x8 v; } bu;
#pragma unroll
      for (int j = 0; j < 4; ++j) {
        const unsigned short s0 =
            *(const unsigned short*)(xS + (n0 + 2 * j) * XSTR + dcol);
        const unsigned short s1 =
            *(const unsigned short*)(xS + (n0 + 2 * j + 1) * XSTR + dcol);
        bu.u[j] = (unsigned int)s0 | ((unsigned int)s1 << 16);
      }
#pragma unroll
      for (int mt = 0; mt < 2; ++mt) {
        const int k = (l & 31) + 32 * mt;
        const int cn = n0 >> 2;
        const uint2 lo = *(const uint2*)(aT + k * NT + (((cn)     ^ (k & 15)) << 2));
        const uint2 hi = *(const uint2*)(aT + k * NT + (((cn + 1) ^ (k & 15)) << 2));
        union { unsigned int u[4]; bf16x8 v; } au;
        au.u[0] = lo.x; au.u[1] = lo.y; au.u[2] = hi.x; au.u[3] = hi.y;
        acc2[mt] = __builtin_amdgcn_mfma_f32_32x32x16_bf16(au.v, bu.v,
                                                           acc2[mt], 0, 0, 0);
      }
    }
    // next iteration's top barrier protects xS/aT before overwrite
  }

  // ---- epilogue: asum combine + atomic accumulation into acc[B][K][D] ----
#pragma unroll
  for (int nt = 0; nt < 4; ++nt)
    if (l < 16) asumS[w * 64 + nt * 16 + (l & 15)] = asum_acc[nt];
  __syncthreads();
  if (tid < 64)
    atomicAdd(&asumA[(size_t)b * Kc + tid],
              asumS[tid] + asumS[64 + tid] + asumS[128 + tid] + asumS[192 + tid]);

  float* ap = accA + (size_t)b * (Kc * Dc);
#pragma unroll
  for (int mt = 0; mt < 2; ++mt)
#pragma unroll
    for (int r = 0; r < 16; ++r) {
      const int k = 32 * mt + (r & 3) + 8 * (r >> 2) + 4 * (l >> 5);
      atomicAdd(&ap[k * Dc + dcol], acc2[mt][r]);
    }
}

// ---------------------------------------------------------------------------
// Kernel 2: subtract centroid*asum, intra-normalize over D, write out;
// emit per-(b,kg) sum-of-squares for the global norm.
// ---------------------------------------------------------------------------
__global__ __launch_bounds__(256) void nv_k2(
    const float* __restrict__ accA, const float* __restrict__ asumA,
    const float* __restrict__ cent, float* __restrict__ out,
    float* __restrict__ gssP) {
  __shared__ float asumS[8];
  __shared__ float gssWv[4];
  const int tid = threadIdx.x;
  const int w = tid >> 6, l = tid & 63;
  const int b = blockIdx.x >> 3;
  const int kg = blockIdx.x & 7;

  if (tid < 8) asumS[tid] = asumA[(size_t)b * Kc + kg * 8 + tid];
  __syncthreads();

  float gss = 0.f;
#pragma unroll
  for (int ki = 0; ki < 2; ++ki) {
    const int kloc = w + 4 * ki, k = kg * 8 + kloc;
    const float2 t = *(const float2*)(accA + (size_t)b * (Kc * Dc) + k * Dc + 2 * l);
    const float as = asumS[kloc];
    const float2 c2 = *(const float2*)(cent + (size_t)k * Dc + 2 * l);
    float v0 = t.x - c2.x * as;
    float v1 = t.y - c2.y * as;
    float ssk = v0 * v0 + v1 * v1;
#pragma unroll
    for (int o = 1; o < 64; o <<= 1) ssk += __shfl_xor(ssk, o);
    const float sc = 1.0f / fmaxf(sqrtf(ssk), 1e-12f);
    gss += ssk * sc * sc;
    float2* o2 =
        reinterpret_cast<float2*>(out + (size_t)b * (Kc * Dc) + k * Dc + 2 * l);
    *o2 = make_float2(v0 * sc, v1 * sc);
  }
  if (l == 0) gssWv[w] = gss;
  __syncthreads();
  if (tid == 0) gssP[blockIdx.x] = gssWv[0] + gssWv[1] + gssWv[2] + gssWv[3];
}

// ---------------------------------------------------------------------------
// Kernel 3: global L2 normalization.
// ---------------------------------------------------------------------------
__global__ __launch_bounds__(256) void nv_k3(float* __restrict__ out,
                                             const float* __restrict__ gssP) {
  const int bid = blockIdx.x;
  const int b = bid >> 3;
  float g = 0.f;
#pragma unroll
  for (int i = 0; i < 8; ++i) g += gssP[b * 8 + i];
  const float gsc = 1.0f / fmaxf(sqrtf(g), 1e-12f);
  float4* o4 = reinterpret_cast<float4*>(out) + (size_t)bid * 256 + threadIdx.x;
  float4 v = *o4;
  v.x *= gsc;
  v.y *= gsc;
  v.z *= gsc;
  v.w *= gsc;
  *o4 = v;
}

}  // namespace

extern "C" void kernel_launch(void* const* d_in, const int* in_sizes, int n_in,
                              void* d_out, int out_size, void* d_ws,
                              size_t ws_size, hipStream_t stream) {
  const float* x = (const float*)d_in[0];
  const float* ce = (const float*)d_in[1];
  const float* cw = (const float*)d_in[2];
  const float* cb = (const float*)d_in[3];
  float* out = (float*)d_out;

  const size_t accf = (size_t)Bc * Kc * Dc;  // 262144 floats (1 MB)
  const size_t asumf = (size_t)Bc * Kc;      // 2048 floats
  const size_t gssf = (size_t)Bc * 8;        // 256 floats
  float* accA = (float*)d_ws;
  float* asumA = accA + accf;
  float* gssP = asumA + asumf;
  uint4* wpk = (uint4*)(gssP + gssf);        // 1024 x 16 B = 16 KB

  (void)hipMemsetAsync(d_ws, 0, (accf + asumf) * sizeof(float), stream);
  nv_k0<<<4, 256, 0, stream>>>(cw, wpk);
  nv_k1<<<Bc * PB, 256, 0, stream>>>(x, wpk, cb, accA, asumA);
  nv_k2<<<Bc * 8, 256, 0, stream>>>(accA, asumA, ce, out, gssP);
  nv_k3<<<256, 256, 0, stream>>>(out, gssP);
}

// Round 7
// 82.237 us; speedup vs baseline: 1.3465x; 1.1741x over previous
//
#include <hip/hip_runtime.h>
#include <hip/hip_bf16.h>
#include <math.h>

namespace {

typedef float f32x4 __attribute__((ext_vector_type(4)));
typedef float f32x16 __attribute__((ext_vector_type(16)));
typedef short bf16x8 __attribute__((ext_vector_type(8)));

constexpr int Bc = 32, Nc = 8192, Dc = 128, Kc = 64;
constexpr int PB = 32;            // blocks per batch
constexpr int RPB = Nc / PB;      // 256 rows per block
constexpr int NT = 64;            // rows per iteration tile
constexpr int ITERS = RPB / NT;   // 4
constexpr int XSTR = 136;         // xS row stride in shorts (272 B, 16B-aligned)

// packed bf16 pair via v_cvt_pk_bf16_f32 (compiler-emitted, RNE)
__device__ __forceinline__ unsigned int pk(float a, float b) {
  union { __hip_bfloat162 h; unsigned int u; } c;
  c.h = __float22bfloat162_rn(make_float2(a, b));
  return c.u;
}

// ---------------------------------------------------------------------------
// Kernel 0: pre-pack conv_w into GEMM1 B-fragment layout (bf16, uint4 per
// lane-fragment). Table: [nt*4+ks][lane] -> 16 B. Total 16 KB, L2-resident.
// ---------------------------------------------------------------------------
__global__ __launch_bounds__(256) void nv_k0(const float* __restrict__ conv_w,
                                             uint4* __restrict__ wpk) {
  const int t = blockIdx.x * 256 + threadIdx.x;  // 0..1023
  const int lane = t & 63, frag = t >> 6;        // frag = nt*4+ks
  const int nt = frag >> 2, ks = frag & 3;
  const int k = (lane & 15) + 16 * nt;
  const float* wp = conv_w + k * Dc + 8 * (lane >> 4) + 32 * ks;
  const float4 w0 = *(const float4*)wp;
  const float4 w1 = *(const float4*)(wp + 4);
  wpk[frag * 64 + lane] =
      make_uint4(pk(w0.x, w0.y), pk(w0.z, w0.w), pk(w1.x, w1.y), pk(w1.z, w1.w));
}

// ---------------------------------------------------------------------------
// Kernel 1: per 64-row tile: load -> L2-normalize -> bf16 LDS tile -> MFMA
// logits (W fragments from L2 table) -> in-wave softmax -> swizzled a^T tile
// -> MFMA a^T x. Block = 256 threads (4 waves). min-waves=3 keeps the unified
// VGPR budget at ~170 so the accumulator block + working set fit WITHOUT
// scratch spill (the (256,4)=128 budget forced arch-VGPR=64 + loop spills).
// ---------------------------------------------------------------------------
__global__ __launch_bounds__(256, 3) void nv_k1(
    const float* __restrict__ x, const uint4* __restrict__ wpk,
    const float* __restrict__ conv_b, float* __restrict__ accA,
    float* __restrict__ asumA) {
  __shared__ __align__(16) short xS[NT * XSTR];  // xn tile, bf16
  __shared__ __align__(16) short aT[Kc * NT];    // a^T tile, bf16, chunk-swizzled
  __shared__ float asumS[4 * 64];

  const int tid = threadIdx.x;
  const int w = tid >> 6, l = tid & 63;
  const int bp = blockIdx.x;  // 0..1023
  const int b = bp / PB, p = bp % PB;
  const float* xb = x + (size_t)b * Nc * Dc + (size_t)p * RPB * Dc;

  // bias per nt (lane's cluster k = (l&15)+16nt)
  float cb[4];
#pragma unroll
  for (int nt = 0; nt < 4; ++nt) cb[nt] = conv_b[(l & 15) + 16 * nt];

  f32x16 acc2[2];
#pragma unroll
  for (int mt = 0; mt < 2; ++mt)
#pragma unroll
    for (int r = 0; r < 16; ++r) acc2[mt][r] = 0.f;
  float asum_acc[4] = {0.f, 0.f, 0.f, 0.f};

  // staging: thread owns row sr (0..63), quarter sq (32 floats, contiguous)
  const int sr = tid >> 2, sq = tid & 3;
  const int dcol = (l & 31) + 32 * w;  // this lane's output d-column (GEMM2)

  for (int it = 0; it < ITERS; ++it) {
    // ---- load tile (no persistent prefetch; TLP hides latency) ----
    float4 cur[8];
    {
      const float* gp = xb + (size_t)(it * NT + sr) * Dc + 32 * sq;
#pragma unroll
      for (int j = 0; j < 8; ++j) cur[j] = *(const float4*)(gp + 4 * j);
    }
    // ---- normalize (4-lane shfl reduce) ----
    float ss = 0.f;
#pragma unroll
    for (int j = 0; j < 8; ++j)
      ss += cur[j].x * cur[j].x + cur[j].y * cur[j].y +
            cur[j].z * cur[j].z + cur[j].w * cur[j].w;
    ss += __shfl_xor(ss, 1);
    ss += __shfl_xor(ss, 2);
    const float invn = 1.0f / fmaxf(sqrtf(ss), 1e-12f);
    __syncthreads();  // previous iteration's GEMM2 done with xS/aT
    {
      // convert + write directly (no register staging buffer)
      short* dst = xS + sr * XSTR + 32 * sq;
#pragma unroll
      for (int j = 0; j < 4; ++j) {
        union { unsigned int u[4]; bf16x8 v; } fu;
        fu.u[0] = pk(cur[2 * j].x * invn, cur[2 * j].y * invn);
        fu.u[1] = pk(cur[2 * j].z * invn, cur[2 * j].w * invn);
        fu.u[2] = pk(cur[2 * j + 1].x * invn, cur[2 * j + 1].y * invn);
        fu.u[3] = pk(cur[2 * j + 1].z * invn, cur[2 * j + 1].w * invn);
        *(bf16x8*)(dst + 8 * j) = fu.v;
      }
    }
    __syncthreads();  // xS ready

    // ---- GEMM1: logits[16 rows x 64 k] for wave w; W streamed from L2 ----
    f32x4 c1[4];
#pragma unroll
    for (int nt = 0; nt < 4; ++nt) {
      c1[nt][0] = 0.f; c1[nt][1] = 0.f; c1[nt][2] = 0.f; c1[nt][3] = 0.f;
    }
#pragma unroll
    for (int ks = 0; ks < 4; ++ks) {
      const bf16x8 af =
          *(const bf16x8*)(xS + (16 * w + (l & 15)) * XSTR + 8 * (l >> 4) + 32 * ks);
      union { uint4 q; bf16x8 v; } wu0, wu1, wu2, wu3;
      wu0.q = wpk[(0 * 4 + ks) * 64 + l];
      wu1.q = wpk[(1 * 4 + ks) * 64 + l];
      wu2.q = wpk[(2 * 4 + ks) * 64 + l];
      wu3.q = wpk[(3 * 4 + ks) * 64 + l];
      c1[0] = __builtin_amdgcn_mfma_f32_16x16x32_bf16(af, wu0.v, c1[0], 0, 0, 0);
      c1[1] = __builtin_amdgcn_mfma_f32_16x16x32_bf16(af, wu1.v, c1[1], 0, 0, 0);
      c1[2] = __builtin_amdgcn_mfma_f32_16x16x32_bf16(af, wu2.v, c1[2], 0, 0, 0);
      c1[3] = __builtin_amdgcn_mfma_f32_16x16x32_bf16(af, wu3.v, c1[3], 0, 0, 0);
    }

    // ---- softmax (in-lane + 16-lane-group shfl); rows n = 16w+4*(l>>4)+i ----
    float a4[4][4];
#pragma unroll
    for (int nt = 0; nt < 4; ++nt)
#pragma unroll
      for (int i = 0; i < 4; ++i) a4[nt][i] = c1[nt][i] + cb[nt];
#pragma unroll
    for (int i = 0; i < 4; ++i) {
      float mx = fmaxf(fmaxf(a4[0][i], a4[1][i]), fmaxf(a4[2][i], a4[3][i]));
      mx = fmaxf(mx, __shfl_xor(mx, 1));
      mx = fmaxf(mx, __shfl_xor(mx, 2));
      mx = fmaxf(mx, __shfl_xor(mx, 4));
      mx = fmaxf(mx, __shfl_xor(mx, 8));
      float s = 0.f;
#pragma unroll
      for (int nt = 0; nt < 4; ++nt) {
        a4[nt][i] = __expf(a4[nt][i] - mx);
        s += a4[nt][i];
      }
      s += __shfl_xor(s, 1);
      s += __shfl_xor(s, 2);
      s += __shfl_xor(s, 4);
      s += __shfl_xor(s, 8);
      const float inv = __builtin_amdgcn_rcpf(s);
#pragma unroll
      for (int nt = 0; nt < 4; ++nt) a4[nt][i] *= inv;
    }
    // ---- asum accumulate + a^T tile write (swizzled chunks) ----
#pragma unroll
    for (int nt = 0; nt < 4; ++nt) {
      float s = a4[nt][0] + a4[nt][1] + a4[nt][2] + a4[nt][3];
      s += __shfl_xor(s, 16);
      s += __shfl_xor(s, 32);
      asum_acc[nt] += s;
      const int k = (l & 15) + 16 * nt;
      const int cn = 4 * w + (l >> 4);  // n-chunk (4 rows)
      const unsigned int u0 = pk(a4[nt][0], a4[nt][1]);
      const unsigned int u1 = pk(a4[nt][2], a4[nt][3]);
      *(uint2*)(aT + k * NT + ((cn ^ (l & 15)) << 2)) = make_uint2(u0, u1);
    }
    __syncthreads();  // aT ready

    // ---- GEMM2: acc[k][d] += a^T[k][n] * xn[n][d], 32x32x16 ----
#pragma unroll
    for (int ks2 = 0; ks2 < 4; ++ks2) {
      const int n0 = 16 * ks2 + 8 * (l >> 5);
      union { unsigned int u[4]; bf16x8 v; } bu;
#pragma unroll
      for (int j = 0; j < 4; ++j) {
        const unsigned short s0 =
            *(const unsigned short*)(xS + (n0 + 2 * j) * XSTR + dcol);
        const unsigned short s1 =
            *(const unsigned short*)(xS + (n0 + 2 * j + 1) * XSTR + dcol);
        bu.u[j] = (unsigned int)s0 | ((unsigned int)s1 << 16);
      }
#pragma unroll
      for (int mt = 0; mt < 2; ++mt) {
        const int k = (l & 31) + 32 * mt;
        const int cn = n0 >> 2;
        const uint2 lo = *(const uint2*)(aT + k * NT + (((cn)     ^ (k & 15)) << 2));
        const uint2 hi = *(const uint2*)(aT + k * NT + (((cn + 1) ^ (k & 15)) << 2));
        union { unsigned int u[4]; bf16x8 v; } au;
        au.u[0] = lo.x; au.u[1] = lo.y; au.u[2] = hi.x; au.u[3] = hi.y;
        acc2[mt] = __builtin_amdgcn_mfma_f32_32x32x16_bf16(au.v, bu.v,
                                                           acc2[mt], 0, 0, 0);
      }
    }
    // next iteration's top barrier protects xS/aT before overwrite
  }

  // ---- epilogue: asum combine + atomic accumulation into acc[B][K][D] ----
#pragma unroll
  for (int nt = 0; nt < 4; ++nt)
    if (l < 16) asumS[w * 64 + nt * 16 + (l & 15)] = asum_acc[nt];
  __syncthreads();
  if (tid < 64)
    atomicAdd(&asumA[(size_t)b * Kc + tid],
              asumS[tid] + asumS[64 + tid] + asumS[128 + tid] + asumS[192 + tid]);

  float* ap = accA + (size_t)b * (Kc * Dc);
#pragma unroll
  for (int mt = 0; mt < 2; ++mt)
#pragma unroll
    for (int r = 0; r < 16; ++r) {
      const int k = 32 * mt + (r & 3) + 8 * (r >> 2) + 4 * (l >> 5);
      atomicAdd(&ap[k * Dc + dcol], acc2[mt][r]);
    }
}

// ---------------------------------------------------------------------------
// Kernel 2: subtract centroid*asum, intra-normalize over D, write out;
// emit per-(b,kg) sum-of-squares for the global norm.
// ---------------------------------------------------------------------------
__global__ __launch_bounds__(256) void nv_k2(
    const float* __restrict__ accA, const float* __restrict__ asumA,
    const float* __restrict__ cent, float* __restrict__ out,
    float* __restrict__ gssP) {
  __shared__ float asumS[8];
  __shared__ float gssWv[4];
  const int tid = threadIdx.x;
  const int w = tid >> 6, l = tid & 63;
  const int b = blockIdx.x >> 3;
  const int kg = blockIdx.x & 7;

  if (tid < 8) asumS[tid] = asumA[(size_t)b * Kc + kg * 8 + tid];
  __syncthreads();

  float gss = 0.f;
#pragma unroll
  for (int ki = 0; ki < 2; ++ki) {
    const int kloc = w + 4 * ki, k = kg * 8 + kloc;
    const float2 t = *(const float2*)(accA + (size_t)b * (Kc * Dc) + k * Dc + 2 * l);
    const float as = asumS[kloc];
    const float2 c2 = *(const float2*)(cent + (size_t)k * Dc + 2 * l);
    float v0 = t.x - c2.x * as;
    float v1 = t.y - c2.y * as;
    float ssk = v0 * v0 + v1 * v1;
#pragma unroll
    for (int o = 1; o < 64; o <<= 1) ssk += __shfl_xor(ssk, o);
    const float sc = 1.0f / fmaxf(sqrtf(ssk), 1e-12f);
    gss += ssk * sc * sc;
    float2* o2 =
        reinterpret_cast<float2*>(out + (size_t)b * (Kc * Dc) + k * Dc + 2 * l);
    *o2 = make_float2(v0 * sc, v1 * sc);
  }
  if (l == 0) gssWv[w] = gss;
  __syncthreads();
  if (tid == 0) gssP[blockIdx.x] = gssWv[0] + gssWv[1] + gssWv[2] + gssWv[3];
}

// ---------------------------------------------------------------------------
// Kernel 3: global L2 normalization.
// ---------------------------------------------------------------------------
__global__ __launch_bounds__(256) void nv_k3(float* __restrict__ out,
                                             const float* __restrict__ gssP) {
  const int bid = blockIdx.x;
  const int b = bid >> 3;
  float g = 0.f;
#pragma unroll
  for (int i = 0; i < 8; ++i) g += gssP[b * 8 + i];
  const float gsc = 1.0f / fmaxf(sqrtf(g), 1e-12f);
  float4* o4 = reinterpret_cast<float4*>(out) + (size_t)bid * 256 + threadIdx.x;
  float4 v = *o4;
  v.x *= gsc;
  v.y *= gsc;
  v.z *= gsc;
  v.w *= gsc;
  *o4 = v;
}

}  // namespace

extern "C" void kernel_launch(void* const* d_in, const int* in_sizes, int n_in,
                              void* d_out, int out_size, void* d_ws,
                              size_t ws_size, hipStream_t stream) {
  const float* x = (const float*)d_in[0];
  const float* ce = (const float*)d_in[1];
  const float* cw = (const float*)d_in[2];
  const float* cb = (const float*)d_in[3];
  float* out = (float*)d_out;

  const size_t accf = (size_t)Bc * Kc * Dc;  // 262144 floats (1 MB)
  const size_t asumf = (size_t)Bc * Kc;      // 2048 floats
  const size_t gssf = (size_t)Bc * 8;        // 256 floats
  float* accA = (float*)d_ws;
  float* asumA = accA + accf;
  float* gssP = asumA + asumf;
  uint4* wpk = (uint4*)(gssP + gssf);        // 1024 x 16 B = 16 KB

  (void)hipMemsetAsync(d_ws, 0, (accf + asumf) * sizeof(float), stream);
  nv_k0<<<4, 256, 0, stream>>>(cw, wpk);
  nv_k1<<<Bc * PB, 256, 0, stream>>>(x, wpk, cb, accA, asumA);
  nv_k2<<<Bc * 8, 256, 0, stream>>>(accA, asumA, ce, out, gssP);
  nv_k3<<<256, 256, 0, stream>>>(out, gssP);
}

// Round 8
// 72.255 us; speedup vs baseline: 1.5325x; 1.1382x over previous
//
#include <hip/hip_runtime.h>
#include <hip/hip_bf16.h>
#include <math.h>

namespace {

typedef float f32x4 __attribute__((ext_vector_type(4)));
typedef float f32x16 __attribute__((ext_vector_type(16)));
typedef short bf16x8 __attribute__((ext_vector_type(8)));

constexpr int Bc = 32, Nc = 8192, Dc = 128, Kc = 64;
constexpr int PB = 32;            // blocks per batch (grid = 1024 = 4/CU)
constexpr int RPB = Nc / PB;      // 256 rows per block
constexpr int NT = 64;            // rows per iteration tile
constexpr int ITERS = RPB / NT;   // 4
constexpr int XSTR = 136;         // xS row stride in shorts (272 B, 16B-aligned)

// packed bf16 pair via v_cvt_pk_bf16_f32 (compiler-emitted, RNE)
__device__ __forceinline__ unsigned int pk(float a, float b) {
  union { __hip_bfloat162 h; unsigned int u; } c;
  c.h = __float22bfloat162_rn(make_float2(a, b));
  return c.u;
}

// ---------------------------------------------------------------------------
// Kernel 1 (round-2 structure): per 64-row tile: L2-normalize -> bf16 LDS
// tile -> MFMA logits (conv_w held in registers) -> in-wave softmax (no
// max-subtract: |logit| <= ~2 since |xn|=1, |w_k|~1) -> swizzled a^T tile ->
// MFMA a^T x. 4 waves/block; persistent register prefetch hides HBM latency.
// NO __launch_bounds__ min-waves: compiler picks ~128 VGPR, no spill
// ((256,4) forced arch-VGPR=64 + ~90MB scratch traffic in rounds 4-6).
// ---------------------------------------------------------------------------
__global__ __launch_bounds__(256) void nv_k1(
    const float* __restrict__ x, const float* __restrict__ conv_w,
    const float* __restrict__ conv_b, float* __restrict__ accA,
    float* __restrict__ asumA) {
  __shared__ __align__(16) short xS[NT * XSTR];  // xn tile, bf16
  __shared__ __align__(16) short aT[Kc * NT];    // a^T tile, bf16, chunk-swizzled
  __shared__ float asumS[4 * 64];

  const int tid = threadIdx.x;
  const int w = tid >> 6, l = tid & 63;
  const int bp = blockIdx.x;  // 0..1023
  const int b = bp / PB, p = bp % PB;
  const float* xb = x + (size_t)b * Nc * Dc + (size_t)p * RPB * Dc;

  // --- conv_w fragments (bf16, B-operand of GEMM1) + bias, held in regs ---
  bf16x8 wf[4][4];
  float cb[4];
#pragma unroll
  for (int nt = 0; nt < 4; ++nt) {
    const int k = (l & 15) + 16 * nt;
    cb[nt] = conv_b[k];
#pragma unroll
    for (int ks = 0; ks < 4; ++ks) {
      const float* wp = conv_w + k * Dc + 8 * (l >> 4) + 32 * ks;
      const float4 w0 = *(const float4*)wp;
      const float4 w1 = *(const float4*)(wp + 4);
      union { unsigned int u[4]; bf16x8 v; } fu;
      fu.u[0] = pk(w0.x, w0.y); fu.u[1] = pk(w0.z, w0.w);
      fu.u[2] = pk(w1.x, w1.y); fu.u[3] = pk(w1.z, w1.w);
      wf[nt][ks] = fu.v;
    }
  }

  f32x16 acc2[2];
#pragma unroll
  for (int mt = 0; mt < 2; ++mt)
#pragma unroll
    for (int r = 0; r < 16; ++r) acc2[mt][r] = 0.f;
  float asum_acc[4] = {0.f, 0.f, 0.f, 0.f};

  // staging: thread owns row sr (0..63), quarter sq (32 floats, contiguous)
  const int sr = tid >> 2, sq = tid & 3;
  float4 cur[8];
  {
    const float* gp = xb + (size_t)sr * Dc + 32 * sq;
#pragma unroll
    for (int j = 0; j < 8; ++j) cur[j] = *(const float4*)(gp + 4 * j);
  }

  const int dcol = (l & 31) + 32 * w;  // this lane's output d-column (GEMM2)

  for (int it = 0; it < ITERS; ++it) {
    // ---- normalize (4-lane shfl reduce) + cvt to bf16 ----
    float ss = 0.f;
#pragma unroll
    for (int j = 0; j < 8; ++j)
      ss += cur[j].x * cur[j].x + cur[j].y * cur[j].y +
            cur[j].z * cur[j].z + cur[j].w * cur[j].w;
    ss += __shfl_xor(ss, 1);
    ss += __shfl_xor(ss, 2);
    const float invn = 1.0f / fmaxf(sqrtf(ss), 1e-12f);
    unsigned int xv[16];
#pragma unroll
    for (int j = 0; j < 8; ++j) {
      xv[2 * j] = pk(cur[j].x * invn, cur[j].y * invn);
      xv[2 * j + 1] = pk(cur[j].z * invn, cur[j].w * invn);
    }
    __syncthreads();  // previous iteration's GEMM2 done with xS/aT
    {
      short* dst = xS + sr * XSTR + 32 * sq;
#pragma unroll
      for (int j = 0; j < 4; ++j) {
        union { unsigned int u[4]; bf16x8 v; } fu;
        fu.u[0] = xv[4 * j]; fu.u[1] = xv[4 * j + 1];
        fu.u[2] = xv[4 * j + 2]; fu.u[3] = xv[4 * j + 3];
        *(bf16x8*)(dst + 8 * j) = fu.v;
      }
    }
    // prefetch next 4-row group (hides HBM latency under GEMM phases)
    float4 nxt[8];
    if (it + 1 < ITERS) {
      const float* gp = xb + (size_t)((it + 1) * NT + sr) * Dc + 32 * sq;
#pragma unroll
      for (int j = 0; j < 8; ++j) nxt[j] = *(const float4*)(gp + 4 * j);
    }
    __syncthreads();  // xS ready

    // ---- GEMM1: logits[16 rows x 64 k] for wave w; W in registers ----
    f32x4 c1[4];
#pragma unroll
    for (int nt = 0; nt < 4; ++nt) {
      c1[nt][0] = 0.f; c1[nt][1] = 0.f; c1[nt][2] = 0.f; c1[nt][3] = 0.f;
    }
#pragma unroll
    for (int ks = 0; ks < 4; ++ks) {
      const bf16x8 af =
          *(const bf16x8*)(xS + (16 * w + (l & 15)) * XSTR + 8 * (l >> 4) + 32 * ks);
#pragma unroll
      for (int nt = 0; nt < 4; ++nt)
        c1[nt] = __builtin_amdgcn_mfma_f32_16x16x32_bf16(af, wf[nt][ks],
                                                         c1[nt], 0, 0, 0);
    }

    // ---- softmax, NO max-subtract (|logit| <= ~2: |xn|=1, |w_k|~1) ----
    // rows n = 16w + 4*(l>>4) + i; lane group of 16 covers k = (l&15)+16nt
    float a4[4][4];
#pragma unroll
    for (int nt = 0; nt < 4; ++nt)
#pragma unroll
      for (int i = 0; i < 4; ++i) a4[nt][i] = __expf(c1[nt][i] + cb[nt]);
#pragma unroll
    for (int i = 0; i < 4; ++i) {
      float s = a4[0][i] + a4[1][i] + a4[2][i] + a4[3][i];
      s += __shfl_xor(s, 1);
      s += __shfl_xor(s, 2);
      s += __shfl_xor(s, 4);
      s += __shfl_xor(s, 8);
      const float inv = __builtin_amdgcn_rcpf(s);
#pragma unroll
      for (int nt = 0; nt < 4; ++nt) a4[nt][i] *= inv;
    }
    // ---- asum accumulate + a^T tile write (swizzled chunks) ----
#pragma unroll
    for (int nt = 0; nt < 4; ++nt) {
      float s = a4[nt][0] + a4[nt][1] + a4[nt][2] + a4[nt][3];
      s += __shfl_xor(s, 16);
      s += __shfl_xor(s, 32);
      asum_acc[nt] += s;
      const int k = (l & 15) + 16 * nt;
      const int cn = 4 * w + (l >> 4);  // n-chunk (4 rows)
      const unsigned int u0 = pk(a4[nt][0], a4[nt][1]);
      const unsigned int u1 = pk(a4[nt][2], a4[nt][3]);
      *(uint2*)(aT + k * NT + ((cn ^ (l & 15)) << 2)) = make_uint2(u0, u1);
    }
    __syncthreads();  // aT ready

    // ---- GEMM2: acc[k][d] += a^T[k][n] * xn[n][d], 32x32x16 ----
#pragma unroll
    for (int ks2 = 0; ks2 < 4; ++ks2) {
      const int n0 = 16 * ks2 + 8 * (l >> 5);
      union { unsigned int u[4]; bf16x8 v; } bu;
#pragma unroll
      for (int j = 0; j < 4; ++j) {
        const unsigned short s0 =
            *(const unsigned short*)(xS + (n0 + 2 * j) * XSTR + dcol);
        const unsigned short s1 =
            *(const unsigned short*)(xS + (n0 + 2 * j + 1) * XSTR + dcol);
        bu.u[j] = (unsigned int)s0 | ((unsigned int)s1 << 16);
      }
#pragma unroll
      for (int mt = 0; mt < 2; ++mt) {
        const int k = (l & 31) + 32 * mt;
        const int cn = n0 >> 2;
        const uint2 lo = *(const uint2*)(aT + k * NT + (((cn)     ^ (k & 15)) << 2));
        const uint2 hi = *(const uint2*)(aT + k * NT + (((cn + 1) ^ (k & 15)) << 2));
        union { unsigned int u[4]; bf16x8 v; } au;
        au.u[0] = lo.x; au.u[1] = lo.y; au.u[2] = hi.x; au.u[3] = hi.y;
        acc2[mt] = __builtin_amdgcn_mfma_f32_32x32x16_bf16(au.v, bu.v,
                                                           acc2[mt], 0, 0, 0);
      }
    }
    // next iteration's top barrier protects xS/aT before overwrite
#pragma unroll
    for (int j = 0; j < 8; ++j) cur[j] = nxt[j];
  }

  // ---- epilogue: asum combine + atomic accumulation into acc[B][K][D] ----
#pragma unroll
  for (int nt = 0; nt < 4; ++nt)
    if (l < 16) asumS[w * 64 + nt * 16 + (l & 15)] = asum_acc[nt];
  __syncthreads();
  if (tid < 64)
    atomicAdd(&asumA[(size_t)b * Kc + tid],
              asumS[tid] + asumS[64 + tid] + asumS[128 + tid] + asumS[192 + tid]);

  float* ap = accA + (size_t)b * (Kc * Dc);
#pragma unroll
  for (int mt = 0; mt < 2; ++mt)
#pragma unroll
    for (int r = 0; r < 16; ++r) {
      const int k = 32 * mt + (r & 3) + 8 * (r >> 2) + 4 * (l >> 5);
      atomicAdd(&ap[k * Dc + dcol], acc2[mt][r]);
    }
}

// ---------------------------------------------------------------------------
// Kernel 2: subtract centroid*asum, intra-normalize over D, write out;
// emit per-(b,kg) sum-of-squares for the global norm.
// ---------------------------------------------------------------------------
__global__ __launch_bounds__(256) void nv_k2(
    const float* __restrict__ accA, const float* __restrict__ asumA,
    const float* __restrict__ cent, float* __restrict__ out,
    float* __restrict__ gssP) {
  __shared__ float asumS[8];
  __shared__ float gssWv[4];
  const int tid = threadIdx.x;
  const int w = tid >> 6, l = tid & 63;
  const int b = blockIdx.x >> 3;
  const int kg = blockIdx.x & 7;

  if (tid < 8) asumS[tid] = asumA[(size_t)b * Kc + kg * 8 + tid];
  __syncthreads();

  float gss = 0.f;
#pragma unroll
  for (int ki = 0; ki < 2; ++ki) {
    const int kloc = w + 4 * ki, k = kg * 8 + kloc;
    const float2 t = *(const float2*)(accA + (size_t)b * (Kc * Dc) + k * Dc + 2 * l);
    const float as = asumS[kloc];
    const float2 c2 = *(const float2*)(cent + (size_t)k * Dc + 2 * l);
    float v0 = t.x - c2.x * as;
    float v1 = t.y - c2.y * as;
    float ssk = v0 * v0 + v1 * v1;
#pragma unroll
    for (int o = 1; o < 64; o <<= 1) ssk += __shfl_xor(ssk, o);
    const float sc = 1.0f / fmaxf(sqrtf(ssk), 1e-12f);
    gss += ssk * sc * sc;
    float2* o2 =
        reinterpret_cast<float2*>(out + (size_t)b * (Kc * Dc) + k * Dc + 2 * l);
    *o2 = make_float2(v0 * sc, v1 * sc);
  }
  if (l == 0) gssWv[w] = gss;
  __syncthreads();
  if (tid == 0) gssP[blockIdx.x] = gssWv[0] + gssWv[1] + gssWv[2] + gssWv[3];
}

// ---------------------------------------------------------------------------
// Kernel 3: global L2 normalization.
// ---------------------------------------------------------------------------
__global__ __launch_bounds__(256) void nv_k3(float* __restrict__ out,
                                             const float* __restrict__ gssP) {
  const int bid = blockIdx.x;
  const int b = bid >> 3;
  float g = 0.f;
#pragma unroll
  for (int i = 0; i < 8; ++i) g += gssP[b * 8 + i];
  const float gsc = 1.0f / fmaxf(sqrtf(g), 1e-12f);
  float4* o4 = reinterpret_cast<float4*>(out) + (size_t)bid * 256 + threadIdx.x;
  float4 v = *o4;
  v.x *= gsc;
  v.y *= gsc;
  v.z *= gsc;
  v.w *= gsc;
  *o4 = v;
}

}  // namespace

extern "C" void kernel_launch(void* const* d_in, const int* in_sizes, int n_in,
                              void* d_out, int out_size, void* d_ws,
                              size_t ws_size, hipStream_t stream) {
  const float* x = (const float*)d_in[0];
  const float* ce = (const float*)d_in[1];
  const float* cw = (const float*)d_in[2];
  const float* cb = (const float*)d_in[3];
  float* out = (float*)d_out;

  const size_t accf = (size_t)Bc * Kc * Dc;  // 262144 floats (1 MB)
  const size_t asumf = (size_t)Bc * Kc;      // 2048 floats
  float* accA = (float*)d_ws;
  float* asumA = accA + accf;
  float* gssP = asumA + asumf;

  (void)hipMemsetAsync(d_ws, 0, (accf + asumf) * sizeof(float), stream);
  nv_k1<<<Bc * PB, 256, 0, stream>>>(x, cw, cb, accA, asumA);
  nv_k2<<<Bc * 8, 256, 0, stream>>>(accA, asumA, ce, out, gssP);
  nv_k3<<<256, 256, 0, stream>>>(out, gssP);
}

// Round 9
// 65.573 us; speedup vs baseline: 1.6887x; 1.1019x over previous
//
#include <hip/hip_runtime.h>
#include <hip/hip_bf16.h>
#include <math.h>

namespace {

typedef float f32x4 __attribute__((ext_vector_type(4)));
typedef float f32x16 __attribute__((ext_vector_type(16)));
typedef short bf16x8 __attribute__((ext_vector_type(8)));

constexpr int Bc = 32, Nc = 8192, Dc = 128, Kc = 64;
constexpr int PB = 32;            // blocks per batch (grid = 1024)
constexpr int RPB = Nc / PB;      // 256 rows per block
constexpr int NT = 64;            // rows per iteration tile
constexpr int ITERS = RPB / NT;   // 4
constexpr int XSTR = 136;         // xS row stride in shorts (272 B)

// packed bf16 pair via v_cvt_pk_bf16_f32 (compiler-emitted, RNE)
__device__ __forceinline__ unsigned int pk(float a, float b) {
  union { __hip_bfloat162 h; unsigned int u; } c;
  c.h = __float22bfloat162_rn(make_float2(a, b));
  return c.u;
}
__device__ __forceinline__ unsigned short f2b(float f) {
  union { __hip_bfloat16 h; unsigned short u; } c;
  c.h = __float2bfloat16(f);
  return c.u;
}
__device__ __forceinline__ float b2f(unsigned short u) {
  union { unsigned int i; float f; } c;
  c.i = ((unsigned int)u) << 16;
  return c.f;
}

// ---------------------------------------------------------------------------
// Kernel 1: per 64-row tile: L2-normalize -> bf16 LDS tile -> SWAPPED MFMA
// logits C[k][n] (W as A-operand; A/B frags are lane-symmetric so wf/af are
// unchanged) -> 2-shfl softmax (16 in-lane k-values + xor16/xor32 over the
// 4 k-groups) -> aT scalar b16 writes (same swizzled layout as before) ->
// asum via post-barrier aT row-reduce (off critical path) -> MFMA a^T x.
// Epilogue: plain partial stores (NO atomics — 8.4M contended atomicAdds
// cost ~20+ us in rounds 3-8).
// ---------------------------------------------------------------------------
__global__ __launch_bounds__(256) void nv_k1(
    const float* __restrict__ x, const float* __restrict__ conv_w,
    const float* __restrict__ conv_b, float* __restrict__ accP,
    float* __restrict__ asumP) {
  __shared__ __align__(16) short xS[NT * XSTR];  // xn tile, bf16
  __shared__ __align__(16) short aT[Kc * NT];    // a^T tile, bf16, chunk-swizzled

  const int tid = threadIdx.x;
  const int w = tid >> 6, l = tid & 63;
  const int bp = blockIdx.x;  // 0..1023
  const int b = bp / PB, p = bp % PB;
  const float* xb = x + (size_t)b * Nc * Dc + (size_t)p * RPB * Dc;

  // --- conv_w fragments (unchanged layout; now used as the A-operand) ---
  bf16x8 wf[4][4];
#pragma unroll
  for (int nt = 0; nt < 4; ++nt) {
    const int k = (l & 15) + 16 * nt;
#pragma unroll
    for (int ks = 0; ks < 4; ++ks) {
      const float* wp = conv_w + k * Dc + 8 * (l >> 4) + 32 * ks;
      const float4 w0 = *(const float4*)wp;
      const float4 w1 = *(const float4*)(wp + 4);
      union { unsigned int u[4]; bf16x8 v; } fu;
      fu.u[0] = pk(w0.x, w0.y); fu.u[1] = pk(w0.z, w0.w);
      fu.u[2] = pk(w1.x, w1.y); fu.u[3] = pk(w1.z, w1.w);
      wf[nt][ks] = fu.v;
    }
  }
  // bias per (nt,i): this lane's logit rows are k = 16nt + 4*(l>>4) + i
  float cb16[4][4];
#pragma unroll
  for (int nt = 0; nt < 4; ++nt)
#pragma unroll
    for (int i = 0; i < 4; ++i)
      cb16[nt][i] = conv_b[16 * nt + 4 * (l >> 4) + i];

  f32x16 acc2[2];
#pragma unroll
  for (int mt = 0; mt < 2; ++mt)
#pragma unroll
    for (int r = 0; r < 16; ++r) acc2[mt][r] = 0.f;
  float asum_acc = 0.f;  // k = tid>>2 partial (valid after 2-shfl reduce)

  const int sr = tid >> 2, sq = tid & 3;
  float4 cur[8];
  {
    const float* gp = xb + (size_t)sr * Dc + 32 * sq;
#pragma unroll
    for (int j = 0; j < 8; ++j) cur[j] = *(const float4*)(gp + 4 * j);
  }

  const int dcol = (l & 31) + 32 * w;
  const int nmy = 16 * w + (l & 15);  // this lane's softmax column (row index)

  for (int it = 0; it < ITERS; ++it) {
    // ---- normalize (4-lane shfl reduce) + cvt to bf16 ----
    float ss = 0.f;
#pragma unroll
    for (int j = 0; j < 8; ++j)
      ss += cur[j].x * cur[j].x + cur[j].y * cur[j].y +
            cur[j].z * cur[j].z + cur[j].w * cur[j].w;
    ss += __shfl_xor(ss, 1);
    ss += __shfl_xor(ss, 2);
    const float invn = 1.0f / fmaxf(sqrtf(ss), 1e-12f);
    unsigned int xv[16];
#pragma unroll
    for (int j = 0; j < 8; ++j) {
      xv[2 * j] = pk(cur[j].x * invn, cur[j].y * invn);
      xv[2 * j + 1] = pk(cur[j].z * invn, cur[j].w * invn);
    }
    __syncthreads();  // previous iteration's GEMM2/asum done with xS/aT
    {
      short* dst = xS + sr * XSTR + 32 * sq;
#pragma unroll
      for (int j = 0; j < 4; ++j) {
        union { unsigned int u[4]; bf16x8 v; } fu;
        fu.u[0] = xv[4 * j]; fu.u[1] = xv[4 * j + 1];
        fu.u[2] = xv[4 * j + 2]; fu.u[3] = xv[4 * j + 3];
        *(bf16x8*)(dst + 8 * j) = fu.v;
      }
    }
    // prefetch next tile
    float4 nxt[8];
    if (it + 1 < ITERS) {
      const float* gp = xb + (size_t)((it + 1) * NT + sr) * Dc + 32 * sq;
#pragma unroll
      for (int j = 0; j < 8; ++j) nxt[j] = *(const float4*)(gp + 4 * j);
    }
    __syncthreads();  // xS ready

    // ---- GEMM1 (swapped): C[k][n] — lane holds k=16nt+4*(l>>4)+i, n=nmy ----
    f32x4 c1[4];
#pragma unroll
    for (int nt = 0; nt < 4; ++nt) {
      c1[nt][0] = 0.f; c1[nt][1] = 0.f; c1[nt][2] = 0.f; c1[nt][3] = 0.f;
    }
#pragma unroll
    for (int ks = 0; ks < 4; ++ks) {
      const bf16x8 af =
          *(const bf16x8*)(xS + (16 * w + (l & 15)) * XSTR + 8 * (l >> 4) + 32 * ks);
#pragma unroll
      for (int nt = 0; nt < 4; ++nt)
        c1[nt] = __builtin_amdgcn_mfma_f32_16x16x32_bf16(wf[nt][ks], af,
                                                         c1[nt], 0, 0, 0);
    }

    // ---- softmax over k for column nmy: 16 in-lane + 2 shfl ----
    float e[4][4];
    float s = 0.f;
#pragma unroll
    for (int nt = 0; nt < 4; ++nt)
#pragma unroll
      for (int i = 0; i < 4; ++i) {
        e[nt][i] = __expf(c1[nt][i] + cb16[nt][i]);  // |logit|<=~2, no max
        s += e[nt][i];
      }
    s += __shfl_xor(s, 16);
    s += __shfl_xor(s, 32);
    const float inv = __builtin_amdgcn_rcpf(s);

    // ---- aT writes: same swizzled layout as before, scalar b16 stores ----
    {
      const int cn = nmy >> 2, nb = nmy & 3;
#pragma unroll
      for (int nt = 0; nt < 4; ++nt)
#pragma unroll
        for (int i = 0; i < 4; ++i) {
          const int k = 16 * nt + 4 * (l >> 4) + i;
          aT[k * NT + ((cn ^ (k & 15)) << 2) + nb] = (short)f2b(e[nt][i] * inv);
        }
    }
    __syncthreads();  // aT ready

    // ---- asum partial from aT (order-independent row sum; off chain) ----
    {
      const short* rp = aT + (tid >> 2) * NT + (tid & 3) * 16;
      union { uint4 q; unsigned short h[8]; } q0, q1;
      q0.q = *(const uint4*)rp;
      q1.q = *(const uint4*)(rp + 8);
      float ps = 0.f;
#pragma unroll
      for (int j = 0; j < 8; ++j) ps += b2f(q0.h[j]) + b2f(q1.h[j]);
      ps += __shfl_xor(ps, 1);
      ps += __shfl_xor(ps, 2);
      asum_acc += ps;
    }

    // ---- GEMM2: acc[k][d] += a^T[k][n] * xn[n][d], 32x32x16 (unchanged) ----
#pragma unroll
    for (int ks2 = 0; ks2 < 4; ++ks2) {
      const int n0 = 16 * ks2 + 8 * (l >> 5);
      union { unsigned int u[4]; bf16x8 v; } bu;
#pragma unroll
      for (int j = 0; j < 4; ++j) {
        const unsigned short s0 =
            *(const unsigned short*)(xS + (n0 + 2 * j) * XSTR + dcol);
        const unsigned short s1 =
            *(const unsigned short*)(xS + (n0 + 2 * j + 1) * XSTR + dcol);
        bu.u[j] = (unsigned int)s0 | ((unsigned int)s1 << 16);
      }
#pragma unroll
      for (int mt = 0; mt < 2; ++mt) {
        const int k = (l & 31) + 32 * mt;
        const int cn = n0 >> 2;
        const uint2 lo = *(const uint2*)(aT + k * NT + (((cn)     ^ (k & 15)) << 2));
        const uint2 hi = *(const uint2*)(aT + k * NT + (((cn + 1) ^ (k & 15)) << 2));
        union { unsigned int u[4]; bf16x8 v; } au;
        au.u[0] = lo.x; au.u[1] = lo.y; au.u[2] = hi.x; au.u[3] = hi.y;
        acc2[mt] = __builtin_amdgcn_mfma_f32_32x32x16_bf16(au.v, bu.v,
                                                           acc2[mt], 0, 0, 0);
      }
    }
#pragma unroll
    for (int j = 0; j < 8; ++j) cur[j] = nxt[j];
  }

  // ---- epilogue: plain partial stores (no atomics) ----
  if ((tid & 3) == 0) asumP[(size_t)bp * Kc + (tid >> 2)] = asum_acc;
  float* ap = accP + (size_t)bp * (Kc * Dc);
#pragma unroll
  for (int mt = 0; mt < 2; ++mt)
#pragma unroll
    for (int r = 0; r < 16; ++r) {
      const int k = 32 * mt + (r & 3) + 8 * (r >> 2) + 4 * (l >> 5);
      ap[k * Dc + dcol] = acc2[mt][r];
    }
}

// ---------------------------------------------------------------------------
// Kernel 2: one wave per (b,k): reduce 32 partials, subtract centroid*asum,
// intra-normalize over D, write out + per-(b,k) gss.
// ---------------------------------------------------------------------------
__global__ __launch_bounds__(64) void nv_k2(
    const float* __restrict__ accP, const float* __restrict__ asumP,
    const float* __restrict__ cent, float* __restrict__ out,
    float* __restrict__ gssK) {
  const int t = threadIdx.x;
  const int b = blockIdx.x >> 6;
  const int k = blockIdx.x & 63;

  // asum: upper 32 lanes load partials, butterfly within 32-halves
  float av = 0.f;
  if (t >= 32) av = asumP[(size_t)(b * PB + (t - 32)) * Kc + k];
  av += __shfl_xor(av, 1);
  av += __shfl_xor(av, 2);
  av += __shfl_xor(av, 4);
  av += __shfl_xor(av, 8);
  av += __shfl_xor(av, 16);
  const float as = __shfl(av, 32);

  float v0 = 0.f, v1 = 0.f;
#pragma unroll
  for (int pp = 0; pp < PB; ++pp) {
    const float2 tt = *(const float2*)(accP + (size_t)(b * PB + pp) * (Kc * Dc) +
                                       k * Dc + 2 * t);
    v0 += tt.x;
    v1 += tt.y;
  }
  const float2 c2 = *(const float2*)(cent + (size_t)k * Dc + 2 * t);
  v0 -= c2.x * as;
  v1 -= c2.y * as;
  float ssk = v0 * v0 + v1 * v1;
#pragma unroll
  for (int o = 1; o < 64; o <<= 1) ssk += __shfl_xor(ssk, o);
  const float sc = 1.0f / fmaxf(sqrtf(ssk), 1e-12f);
  float2* o2 = reinterpret_cast<float2*>(out + (size_t)b * (Kc * Dc) + k * Dc + 2 * t);
  *o2 = make_float2(v0 * sc, v1 * sc);
  if (t == 0) gssK[(size_t)b * Kc + k] = ssk * sc * sc;
}

// ---------------------------------------------------------------------------
// Kernel 3: global L2 normalization (sum 64 per-k gss per batch).
// ---------------------------------------------------------------------------
__global__ __launch_bounds__(256) void nv_k3(float* __restrict__ out,
                                             const float* __restrict__ gssK) {
  const int bid = blockIdx.x;
  const int b = bid >> 3;
  float g = 0.f;
#pragma unroll
  for (int i = 0; i < 64; ++i) g += gssK[(size_t)b * Kc + i];
  const float gsc = 1.0f / fmaxf(sqrtf(g), 1e-12f);
  float4* o4 = reinterpret_cast<float4*>(out) + (size_t)bid * 256 + threadIdx.x;
  float4 v = *o4;
  v.x *= gsc;
  v.y *= gsc;
  v.z *= gsc;
  v.w *= gsc;
  *o4 = v;
}

}  // namespace

extern "C" void kernel_launch(void* const* d_in, const int* in_sizes, int n_in,
                              void* d_out, int out_size, void* d_ws,
                              size_t ws_size, hipStream_t stream) {
  const float* x = (const float*)d_in[0];
  const float* ce = (const float*)d_in[1];
  const float* cw = (const float*)d_in[2];
  const float* cb = (const float*)d_in[3];
  float* out = (float*)d_out;

  const size_t accPf = (size_t)Bc * PB * Kc * Dc;  // 8.39M floats (33.6 MB)
  const size_t asumPf = (size_t)Bc * PB * Kc;      // 65536 floats
  float* accP = (float*)d_ws;
  float* asumP = accP + accPf;
  float* gssK = asumP + asumPf;                    // Bc*Kc floats

  nv_k1<<<Bc * PB, 256, 0, stream>>>(x, cw, cb, accP, asumP);
  nv_k2<<<Bc * Kc, 64, 0, stream>>>(accP, asumP, ce, out, gssK);
  nv_k3<<<Bc * 8, 256, 0, stream>>>(out, gssK);
}